// Round 9
// baseline (77.068 us; speedup 1.0000x reference)
//
#include <hip/hip_runtime.h>

#define TSD 512      // TS (feature dim)
#define SRC 256
#define TGT 256
#define NB  4        // batch
#define KSCALE 2.885390081777927f   // 2*log2(e): exp2(K*x) == exp(2x)
#define ZMAX 32768.0f               // clamp for exp product (tanh err <= 6.1e-5)

// ---------------------------------------------------------------------------
// Projection GEMM: 64x64 tiles, 16x16 threads, 4x4 micro-tile, BK=16.
// z=0: hpE[r][o]    = exp2(K * (hid . Wh)[r][o])               (row-major)
// z=1: epE[b][o][s] = exp2(K * ((enc . We)[r][o] + bias[o]))   (TRANSPOSED)
// ---------------------------------------------------------------------------
__global__ __launch_bounds__(256) void proj_kernel(
    const float* __restrict__ hid, const float* __restrict__ enc,
    const float* __restrict__ W, const float* __restrict__ bias,
    float* __restrict__ hpE, float* __restrict__ epE)
{
    const int z = blockIdx.z;
    const float* __restrict__ X = z ? enc : hid;
    const int wofs = z ? TSD : 0;

    __shared__ float Xs[16][68];   // [k][m]
    __shared__ float Ws[16][68];   // [k][n]
    __shared__ float tile[64][68]; // [s_local][o_local] transpose staging (z=1)

    const int tx = threadIdx.x, ty = threadIdx.y;
    const int tid = ty * 16 + tx;
    const int o0 = blockIdx.x * 64;
    const int r0 = blockIdx.y * 64;

    const int m  = tid >> 2;        // 0..63
    const int kq = (tid & 3) * 4;   // 0,4,8,12

    float acc[4][4] = {};

    for (int k0 = 0; k0 < TSD; k0 += 16) {
        __syncthreads();
        float4 av = *reinterpret_cast<const float4*>(&X[(r0 + m) * TSD + k0 + kq]);
        float4 wv = *reinterpret_cast<const float4*>(&W[(o0 + m) * (2 * TSD) + wofs + k0 + kq]);
        Xs[kq + 0][m] = av.x; Xs[kq + 1][m] = av.y; Xs[kq + 2][m] = av.z; Xs[kq + 3][m] = av.w;
        Ws[kq + 0][m] = wv.x; Ws[kq + 1][m] = wv.y; Ws[kq + 2][m] = wv.z; Ws[kq + 3][m] = wv.w;
        __syncthreads();
        #pragma unroll
        for (int k = 0; k < 16; ++k) {
            float4 a  = *reinterpret_cast<const float4*>(&Xs[k][ty * 4]);
            float4 bb = *reinterpret_cast<const float4*>(&Ws[k][tx * 4]);
            float ar[4] = {a.x, a.y, a.z, a.w};
            float br[4] = {bb.x, bb.y, bb.z, bb.w};
            #pragma unroll
            for (int i = 0; i < 4; ++i)
                #pragma unroll
                for (int j = 0; j < 4; ++j)
                    acc[i][j] = fmaf(ar[i], br[j], acc[i][j]);
        }
    }

    if (z) {
        const float b0 = bias[o0 + tx * 4 + 0];
        const float b1 = bias[o0 + tx * 4 + 1];
        const float b2 = bias[o0 + tx * 4 + 2];
        const float b3 = bias[o0 + tx * 4 + 3];
        __syncthreads();
        #pragma unroll
        for (int i = 0; i < 4; ++i) {
            float4 val;
            val.x = __builtin_amdgcn_exp2f((acc[i][0] + b0) * KSCALE);
            val.y = __builtin_amdgcn_exp2f((acc[i][1] + b1) * KSCALE);
            val.z = __builtin_amdgcn_exp2f((acc[i][2] + b2) * KSCALE);
            val.w = __builtin_amdgcn_exp2f((acc[i][3] + b3) * KSCALE);
            *reinterpret_cast<float4*>(&tile[ty * 4 + i][tx * 4]) = val;
        }
        __syncthreads();
        const int bb_ = r0 >> 8;              // batch of this row-tile
        const int s0  = (r0 & 255) + (tid & 15) * 4;
        #pragma unroll
        for (int it = 0; it < 4; ++it) {
            const int ol = it * 16 + (tid >> 4);
            float4 val;
            val.x = tile[(tid & 15) * 4 + 0][ol];
            val.y = tile[(tid & 15) * 4 + 1][ol];
            val.z = tile[(tid & 15) * 4 + 2][ol];
            val.w = tile[(tid & 15) * 4 + 3][ol];
            *reinterpret_cast<float4*>(&epE[((size_t)bb_ * TSD + o0 + ol) * SRC + s0]) = val;
        }
    } else {
        #pragma unroll
        for (int i = 0; i < 4; ++i) {
            const int r = r0 + ty * 4 + i;
            float4 o4;
            o4.x = __builtin_amdgcn_exp2f(acc[i][0] * KSCALE);
            o4.y = __builtin_amdgcn_exp2f(acc[i][1] * KSCALE);
            o4.z = __builtin_amdgcn_exp2f(acc[i][2] * KSCALE);
            o4.w = __builtin_amdgcn_exp2f(acc[i][3] * KSCALE);
            *reinterpret_cast<float4*>(&hpE[r * TSD + o0 + tx * 4]) = o4;
        }
    }
}

__device__ __forceinline__ float wave_red_sum(float v) {
    #pragma unroll
    for (int off = 1; off < 64; off <<= 1) v += __shfl_xor(v, off, 64);
    return v;
}
__device__ __forceinline__ float wave_red_max(float v) {
    #pragma unroll
    for (int off = 1; off < 64; off <<= 1) v = fmaxf(v, __shfl_xor(v, off, 64));
    return v;
}

// ---------------------------------------------------------------------------
// Phase A: P[t][s] = sum_o v[o]/(z+1), z = min(Eh[t][o]*Ee[o][s], ZMAX).
// Grid (TGT/4, NB, 2 s-halves), 512 thr = 8 waves (o-split 64/wave).
// Lane owns 2 consecutive s (float2 epE loads); 4 t-rows share one rcp.
// Output P -> probs region of d_out (disjoint per block; Phase B finalizes).
// ---------------------------------------------------------------------------
__global__ __launch_bounds__(512) void score_kernel(
    const float* __restrict__ hpE, const float* __restrict__ epE,
    const float* __restrict__ v, float* __restrict__ P_out)
{
    __shared__ float4 eh4[TSD];         // {Eh[t0..t0+3][o]}  (8 KB)
    __shared__ float v_lds[TSD];        // v[o]               (2 KB)
    __shared__ float accs[4][8][128];   // [t][wave][s_local] (16 KB)

    const int tid = threadIdx.x;
    const int b  = blockIdx.y;
    const int t0 = blockIdx.x * 4;
    const int sh = blockIdx.z;          // s-half

    // stage Eh (exp2 pre-applied) for 4 rows + v
    {
        const int row = tid >> 7;            // 0..3
        const int oq  = (tid & 127) * 4;
        const float4 hh = *reinterpret_cast<const float4*>(
            &hpE[((size_t)(b * TGT + t0 + row)) * TSD + oq]);
        ((float*)&eh4[oq + 0])[row] = hh.x;
        ((float*)&eh4[oq + 1])[row] = hh.y;
        ((float*)&eh4[oq + 2])[row] = hh.z;
        ((float*)&eh4[oq + 3])[row] = hh.w;
        v_lds[tid] = v[tid];
    }
    __syncthreads();

    const int w    = __builtin_amdgcn_readfirstlane(tid >> 6);  // wave 0..7
    const int lane = tid & 63;
    const float* __restrict__ epb =
        epE + (size_t)b * TSD * SRC + (size_t)(w * 64) * SRC + sh * 128 + 2 * lane;

    float acc[4][2] = {};   // [t][s-sub]
    #pragma unroll 4
    for (int oi = 0; oi < 64; ++oi) {
        const int o = w * 64 + oi;
        const float2 ee = *reinterpret_cast<const float2*>(epb + (size_t)oi * SRC);
        const float4 eh = eh4[o];       // uniform -> ds_read_b128 broadcast
        const float  vv = v_lds[o];     // uniform -> ds_read_b32 broadcast
        const float eer[2] = {ee.x, ee.y};
        #pragma unroll
        for (int k = 0; k < 2; ++k) {
            const float e = eer[k];
            float z0 = fminf(eh.x * e, ZMAX) + 1.f;
            float z1 = fminf(eh.y * e, ZMAX) + 1.f;
            float z2 = fminf(eh.z * e, ZMAX) + 1.f;
            float z3 = fminf(eh.w * e, ZMAX) + 1.f;
            const float p01 = z0 * z1;
            const float p23 = z2 * z3;
            const float r   = __builtin_amdgcn_rcpf(p01 * p23);
            const float rp01 = r * p01;       // = 1/p23
            const float rp23 = r * p23;       // = 1/p01
            acc[0][k] = fmaf(vv, z1 * rp23, acc[0][k]);
            acc[1][k] = fmaf(vv, z0 * rp23, acc[1][k]);
            acc[2][k] = fmaf(vv, z3 * rp01, acc[2][k]);
            acc[3][k] = fmaf(vv, z2 * rp01, acc[3][k]);
        }
    }
    #pragma unroll
    for (int t = 0; t < 4; ++t) {
        float2 r2; r2.x = acc[t][0]; r2.y = acc[t][1];
        *reinterpret_cast<float2*>(&accs[t][w][2 * lane]) = r2;
    }
    __syncthreads();

    // combine 8 waves, write P: thread owns (t = tid>>7, s = tid&127)
    {
        const int t = tid >> 7;
        const int s = tid & 127;
        float Psum = 0.f;
        #pragma unroll
        for (int k = 0; k < 8; ++k) Psum += accs[t][k][s];
        P_out[((size_t)(b * TGT + t0 + t)) * SRC + sh * 128 + s] = Psum;
    }
}

// ---------------------------------------------------------------------------
// Phase B: softmax. One wave per target row (4 rows/block).
// Reads P from the probs region, overwrites it with final probs.
// ---------------------------------------------------------------------------
__global__ __launch_bounds__(256) void softmax_kernel(
    const int* __restrict__ mask, const float* __restrict__ v,
    float* __restrict__ probs)
{
    const int tid  = threadIdx.x;
    const int lane = tid & 63;
    const int rowg = blockIdx.x * 4 + (tid >> 6);   // global row: b*TGT + t
    const int b    = rowg >> 8;

    // sumv (each wave computes redundantly)
    float sv = 0.f;
    #pragma unroll
    for (int k = 0; k < 8; ++k) sv += v[lane + 64 * k];
    const float sumv = wave_red_sum(sv);

    const size_t base = (size_t)rowg * SRC + 4 * lane;
    const float4 Pv = *reinterpret_cast<const float4*>(&probs[base]);
    float sc[4];
    sc[0] = sumv - 2.f * Pv.x;
    sc[1] = sumv - 2.f * Pv.y;
    sc[2] = sumv - 2.f * Pv.z;
    sc[3] = sumv - 2.f * Pv.w;

    const float lmax = fmaxf(fmaxf(sc[0], sc[1]), fmaxf(sc[2], sc[3]));
    const float m = wave_red_max(lmax);
    float e[4];
    #pragma unroll
    for (int i = 0; i < 4; ++i) e[i] = __expf(sc[i] - m);
    const float sE = wave_red_sum(e[0] + e[1] + e[2] + e[3]);

    const int4 mk = *reinterpret_cast<const int4*>(&mask[b * SRC + 4 * lane]);
    float mq[4];
    mq[0] = (e[0] / sE) * (float)mk.x;
    mq[1] = (e[1] / sE) * (float)mk.y;
    mq[2] = (e[2] / sE) * (float)mk.z;
    mq[3] = (e[3] / sE) * (float)mk.w;
    const float sM = wave_red_sum(mq[0] + mq[1] + mq[2] + mq[3]);
    const float inv = 1.f / (sM + 1e-12f);
    float4 pv;
    pv.x = mq[0] * inv; pv.y = mq[1] * inv; pv.z = mq[2] * inv; pv.w = mq[3] * inv;
    *reinterpret_cast<float4*>(&probs[base]) = pv;
}

// ---------------------------------------------------------------------------
// Phase C: context. Grid (TGT/4, NB, 2 d-halves), 256 thr.
// Reads FINAL probs (stream-ordered after Phase B).
// ---------------------------------------------------------------------------
__global__ __launch_bounds__(256) void ctx_kernel(
    const float* __restrict__ probs, const float* __restrict__ enc,
    float* __restrict__ ctx_out)
{
    __shared__ float p_lds[4][SRC];

    const int tid = threadIdx.x;
    const int b   = blockIdx.y;
    const int t0  = blockIdx.x * 4;
    const int dh  = blockIdx.z;

    #pragma unroll
    for (int t = 0; t < 4; ++t)
        p_lds[t][tid] = probs[((size_t)(b * TGT + t0 + t)) * SRC + tid];
    __syncthreads();

    const float* __restrict__ encb = enc + (size_t)b * SRC * TSD + dh * 256 + tid;
    float c0 = 0.f, c1 = 0.f, c2 = 0.f, c3 = 0.f;
    #pragma unroll 4
    for (int s2 = 0; s2 < SRC; ++s2) {
        const float ev = encb[(size_t)s2 * TSD];
        c0 = fmaf(p_lds[0][s2], ev, c0);
        c1 = fmaf(p_lds[1][s2], ev, c1);
        c2 = fmaf(p_lds[2][s2], ev, c2);
        c3 = fmaf(p_lds[3][s2], ev, c3);
    }
    const size_t obase = ((size_t)(b * TGT + t0)) * TSD + dh * 256 + tid;
    ctx_out[obase]           = c0;
    ctx_out[obase + TSD]     = c1;
    ctx_out[obase + 2 * TSD] = c2;
    ctx_out[obase + 3 * TSD] = c3;
}

extern "C" void kernel_launch(void* const* d_in, const int* in_sizes, int n_in,
                              void* d_out, int out_size, void* d_ws, size_t ws_size,
                              hipStream_t stream) {
    const float* hid  = (const float*)d_in[0];   // (4,256,512)
    const float* enc  = (const float*)d_in[1];   // (4,256,512)
    const int*   mask = (const int*)  d_in[2];   // (4,256)
    const float* W    = (const float*)d_in[3];   // (512,1024)
    const float* bias = (const float*)d_in[4];   // (512,)
    const float* v    = (const float*)d_in[5];   // (512,)

    float* out   = (float*)d_out;
    float* ctx   = out;                       // 4*256*512
    float* probs = out + NB * TGT * TSD;      // 4*256*256 (holds P, then probs)

    float* hpE = (float*)d_ws;                // 1024*512: exp2(K*h)        2 MB
    float* epE = hpE + NB * TGT * TSD;        // 4*512*256: exp2(K*(e+b))^T 2 MB
                                              // total ws use: 4 MB (proven safe)

    dim3 pb(16, 16);
    dim3 pg(TSD / 64, (NB * TGT) / 64, 2);
    proj_kernel<<<pg, pb, 0, stream>>>(hid, enc, W, bias, hpE, epE);

    dim3 ag(TGT / 4, NB, 2);
    score_kernel<<<ag, 512, 0, stream>>>(hpE, epE, v, probs);

    softmax_kernel<<<dim3(NB * TGT / 4), 256, 0, stream>>>(mask, v, probs);

    dim3 cg(TGT / 4, NB, 2);
    ctx_kernel<<<cg, 256, 0, stream>>>(probs, enc, ctx);
}

// Round 10
// 69.115 us; speedup vs baseline: 1.1151x; 1.1151x over previous
//
#include <hip/hip_runtime.h>

#define TSD 512      // TS (feature dim)
#define SRC 256
#define TGT 256
#define NB  4        // batch
#define KSCALE 2.885390081777927f       // 2*log2(e): exp2(K*x) == exp(2x)
#define SCALE  9.5367431640625e-07f     // 2^-20: overflow headroom for 4-way product
#define EPSV   1e-20f

// ---------------------------------------------------------------------------
// Projection GEMM: 64x64 tiles, 16x16 threads, 4x4 micro-tile, BK=16.
// z=0: hpE2[r][o]   = S * exp2(K*(hid.Wh)[r][o]) / v[o]       (row-major)
// z=1: epE[b][o][s] = exp2(K*((enc.We)[r][o] + bias[o]))      (TRANSPOSED)
// ---------------------------------------------------------------------------
__global__ __launch_bounds__(256) void proj_kernel(
    const float* __restrict__ hid, const float* __restrict__ enc,
    const float* __restrict__ W, const float* __restrict__ bias,
    const float* __restrict__ v,
    float* __restrict__ hpE2, float* __restrict__ epE)
{
    const int z = blockIdx.z;
    const float* __restrict__ X = z ? enc : hid;
    const int wofs = z ? TSD : 0;

    __shared__ float Xs[16][68];   // [k][m]
    __shared__ float Ws[16][68];   // [k][n]
    __shared__ float tile[64][68]; // [s_local][o_local] transpose staging (z=1)

    const int tx = threadIdx.x, ty = threadIdx.y;
    const int tid = ty * 16 + tx;
    const int o0 = blockIdx.x * 64;
    const int r0 = blockIdx.y * 64;

    const int m  = tid >> 2;        // 0..63
    const int kq = (tid & 3) * 4;   // 0,4,8,12

    float acc[4][4] = {};

    for (int k0 = 0; k0 < TSD; k0 += 16) {
        __syncthreads();
        float4 av = *reinterpret_cast<const float4*>(&X[(r0 + m) * TSD + k0 + kq]);
        float4 wv = *reinterpret_cast<const float4*>(&W[(o0 + m) * (2 * TSD) + wofs + k0 + kq]);
        Xs[kq + 0][m] = av.x; Xs[kq + 1][m] = av.y; Xs[kq + 2][m] = av.z; Xs[kq + 3][m] = av.w;
        Ws[kq + 0][m] = wv.x; Ws[kq + 1][m] = wv.y; Ws[kq + 2][m] = wv.z; Ws[kq + 3][m] = wv.w;
        __syncthreads();
        #pragma unroll
        for (int k = 0; k < 16; ++k) {
            float4 a  = *reinterpret_cast<const float4*>(&Xs[k][ty * 4]);
            float4 bb = *reinterpret_cast<const float4*>(&Ws[k][tx * 4]);
            float ar[4] = {a.x, a.y, a.z, a.w};
            float br[4] = {bb.x, bb.y, bb.z, bb.w};
            #pragma unroll
            for (int i = 0; i < 4; ++i)
                #pragma unroll
                for (int j = 0; j < 4; ++j)
                    acc[i][j] = fmaf(ar[i], br[j], acc[i][j]);
        }
    }

    if (z) {
        const float b0 = bias[o0 + tx * 4 + 0];
        const float b1 = bias[o0 + tx * 4 + 1];
        const float b2 = bias[o0 + tx * 4 + 2];
        const float b3 = bias[o0 + tx * 4 + 3];
        __syncthreads();
        #pragma unroll
        for (int i = 0; i < 4; ++i) {
            float4 val;
            val.x = __builtin_amdgcn_exp2f((acc[i][0] + b0) * KSCALE);
            val.y = __builtin_amdgcn_exp2f((acc[i][1] + b1) * KSCALE);
            val.z = __builtin_amdgcn_exp2f((acc[i][2] + b2) * KSCALE);
            val.w = __builtin_amdgcn_exp2f((acc[i][3] + b3) * KSCALE);
            *reinterpret_cast<float4*>(&tile[ty * 4 + i][tx * 4]) = val;
        }
        __syncthreads();
        const int bb_ = r0 >> 8;              // batch of this row-tile
        const int s0  = (r0 & 255) + (tid & 15) * 4;
        #pragma unroll
        for (int it = 0; it < 4; ++it) {
            const int ol = it * 16 + (tid >> 4);
            float4 val;
            val.x = tile[(tid & 15) * 4 + 0][ol];
            val.y = tile[(tid & 15) * 4 + 1][ol];
            val.z = tile[(tid & 15) * 4 + 2][ol];
            val.w = tile[(tid & 15) * 4 + 3][ol];
            *reinterpret_cast<float4*>(&epE[((size_t)bb_ * TSD + o0 + ol) * SRC + s0]) = val;
        }
    } else {
        // fold S/v into the exp'd projection
        const int oc = o0 + tx * 4;
        float iv[4];
        #pragma unroll
        for (int j = 0; j < 4; ++j)
            iv[j] = SCALE * __builtin_amdgcn_rcpf(fmaxf(v[oc + j], EPSV));
        #pragma unroll
        for (int i = 0; i < 4; ++i) {
            const int r = r0 + ty * 4 + i;
            float4 o4;
            o4.x = __builtin_amdgcn_exp2f(acc[i][0] * KSCALE) * iv[0];
            o4.y = __builtin_amdgcn_exp2f(acc[i][1] * KSCALE) * iv[1];
            o4.z = __builtin_amdgcn_exp2f(acc[i][2] * KSCALE) * iv[2];
            o4.w = __builtin_amdgcn_exp2f(acc[i][3] * KSCALE) * iv[3];
            *reinterpret_cast<float4*>(&hpE2[r * TSD + oc]) = o4;
        }
    }
}

__device__ __forceinline__ float wave_red_sum(float v) {
    #pragma unroll
    for (int off = 1; off < 64; off <<= 1) v += __shfl_xor(v, off, 64);
    return v;
}
__device__ __forceinline__ float wave_red_max(float v) {
    #pragma unroll
    for (int off = 1; off < 64; off <<= 1) v = fmaxf(v, __shfl_xor(v, off, 64));
    return v;
}

// ---------------------------------------------------------------------------
// Phase A: P[t][s] = sum_o v[o]/(z+1), z = Eh*Ee.
//   w' = Eh2s*Ee + ivs  (ONE fma; v and 2^-20 scale folded into both operands)
//   term = S / w'  ->  P = S * sum(1/w'), 4 t-rows share one rcp.
// Grid (TGT/4, NB, 2 s-halves), 512 thr = 8 waves (o-split 64/wave),
// lane owns 2 consecutive s.  Output -> probs region (Phase B finalizes).
// ---------------------------------------------------------------------------
__global__ __launch_bounds__(512) void score_kernel(
    const float* __restrict__ hpE2, const float* __restrict__ epE,
    const float* __restrict__ v, float* __restrict__ P_out)
{
    __shared__ float4 eh4[TSD];         // Eh2s for 4 t rows   (8 KB)
    __shared__ float ivs[TSD];          // S/v[o]              (2 KB)
    __shared__ float accs[4][8][128];   // [t][wave][s_local]  (16 KB)

    const int tid = threadIdx.x;
    const int b  = blockIdx.y;
    const int t0 = blockIdx.x * 4;
    const int sh = blockIdx.z;          // s-half

    // stage Eh2s (4 rows packed per o) + ivs
    {
        const int row = tid >> 7;            // 0..3
        const int oq  = (tid & 127) * 4;
        const float4 hh = *reinterpret_cast<const float4*>(
            &hpE2[((size_t)(b * TGT + t0 + row)) * TSD + oq]);
        ((float*)&eh4[oq + 0])[row] = hh.x;
        ((float*)&eh4[oq + 1])[row] = hh.y;
        ((float*)&eh4[oq + 2])[row] = hh.z;
        ((float*)&eh4[oq + 3])[row] = hh.w;
        ivs[tid] = SCALE * __builtin_amdgcn_rcpf(fmaxf(v[tid], EPSV));
    }
    __syncthreads();

    const int w    = __builtin_amdgcn_readfirstlane(tid >> 6);  // wave 0..7
    const int lane = tid & 63;
    const float* __restrict__ epb =
        epE + (size_t)b * TSD * SRC + (size_t)(w * 64) * SRC + sh * 128 + 2 * lane;

    float acc[4][2] = {};   // [t][s-sub]
    #pragma unroll 4
    for (int oi = 0; oi < 64; ++oi) {
        const int o = w * 64 + oi;
        const float2 ee = *reinterpret_cast<const float2*>(epb + (size_t)oi * SRC);
        const float4 eh = eh4[o];       // uniform -> ds_read_b128 broadcast
        const float  iv = ivs[o];       // uniform -> ds_read_b32 broadcast
        const float eer[2] = {ee.x, ee.y};
        #pragma unroll
        for (int k = 0; k < 2; ++k) {
            const float e = eer[k];
            const float w0 = fmaf(eh.x, e, iv);
            const float w1 = fmaf(eh.y, e, iv);
            const float w2 = fmaf(eh.z, e, iv);
            const float w3 = fmaf(eh.w, e, iv);
            const float p01 = w0 * w1;
            const float p23 = w2 * w3;
            const float r   = __builtin_amdgcn_rcpf(p01 * p23);
            const float rp01 = r * p01;       // = 1/p23
            const float rp23 = r * p23;       // = 1/p01
            acc[0][k] = fmaf(rp23, w1, acc[0][k]);
            acc[1][k] = fmaf(rp23, w0, acc[1][k]);
            acc[2][k] = fmaf(rp01, w3, acc[2][k]);
            acc[3][k] = fmaf(rp01, w2, acc[3][k]);
        }
    }
    #pragma unroll
    for (int t = 0; t < 4; ++t) {
        float2 r2; r2.x = acc[t][0]; r2.y = acc[t][1];
        *reinterpret_cast<float2*>(&accs[t][w][2 * lane]) = r2;
    }
    __syncthreads();

    // combine 8 waves, write P (re-apply S): thread owns (t = tid>>7, s = tid&127)
    {
        const int t = tid >> 7;
        const int s = tid & 127;
        float Psum = 0.f;
        #pragma unroll
        for (int k = 0; k < 8; ++k) Psum += accs[t][k][s];
        P_out[((size_t)(b * TGT + t0 + t)) * SRC + sh * 128 + s] = Psum * SCALE;
    }
}

// ---------------------------------------------------------------------------
// Phase B: softmax. One wave per target row (4 rows/block).
// Reads P from the probs region, overwrites it with final probs.
// ---------------------------------------------------------------------------
__global__ __launch_bounds__(256) void softmax_kernel(
    const int* __restrict__ mask, const float* __restrict__ v,
    float* __restrict__ probs)
{
    const int tid  = threadIdx.x;
    const int lane = tid & 63;
    const int rowg = blockIdx.x * 4 + (tid >> 6);   // global row: b*TGT + t
    const int b    = rowg >> 8;

    // sumv (each wave computes redundantly)
    float sv = 0.f;
    #pragma unroll
    for (int k = 0; k < 8; ++k) sv += v[lane + 64 * k];
    const float sumv = wave_red_sum(sv);

    const size_t base = (size_t)rowg * SRC + 4 * lane;
    const float4 Pv = *reinterpret_cast<const float4*>(&probs[base]);
    float sc[4];
    sc[0] = sumv - 2.f * Pv.x;
    sc[1] = sumv - 2.f * Pv.y;
    sc[2] = sumv - 2.f * Pv.z;
    sc[3] = sumv - 2.f * Pv.w;

    const float lmax = fmaxf(fmaxf(sc[0], sc[1]), fmaxf(sc[2], sc[3]));
    const float m = wave_red_max(lmax);
    float e[4];
    #pragma unroll
    for (int i = 0; i < 4; ++i) e[i] = __expf(sc[i] - m);
    const float sE = wave_red_sum(e[0] + e[1] + e[2] + e[3]);

    const int4 mk = *reinterpret_cast<const int4*>(&mask[b * SRC + 4 * lane]);
    float mq[4];
    mq[0] = (e[0] / sE) * (float)mk.x;
    mq[1] = (e[1] / sE) * (float)mk.y;
    mq[2] = (e[2] / sE) * (float)mk.z;
    mq[3] = (e[3] / sE) * (float)mk.w;
    const float sM = wave_red_sum(mq[0] + mq[1] + mq[2] + mq[3]);
    const float inv = 1.f / (sM + 1e-12f);
    float4 pv;
    pv.x = mq[0] * inv; pv.y = mq[1] * inv; pv.z = mq[2] * inv; pv.w = mq[3] * inv;
    *reinterpret_cast<float4*>(&probs[base]) = pv;
}

// ---------------------------------------------------------------------------
// Phase C: context. Grid (TGT/4, NB, 2 d-halves), 256 thr.
// Reads FINAL probs (stream-ordered after Phase B).
// ---------------------------------------------------------------------------
__global__ __launch_bounds__(256) void ctx_kernel(
    const float* __restrict__ probs, const float* __restrict__ enc,
    float* __restrict__ ctx_out)
{
    __shared__ float p_lds[4][SRC];

    const int tid = threadIdx.x;
    const int b   = blockIdx.y;
    const int t0  = blockIdx.x * 4;
    const int dh  = blockIdx.z;

    #pragma unroll
    for (int t = 0; t < 4; ++t)
        p_lds[t][tid] = probs[((size_t)(b * TGT + t0 + t)) * SRC + tid];
    __syncthreads();

    const float* __restrict__ encb = enc + (size_t)b * SRC * TSD + dh * 256 + tid;
    float c0 = 0.f, c1 = 0.f, c2 = 0.f, c3 = 0.f;
    #pragma unroll 4
    for (int s2 = 0; s2 < SRC; ++s2) {
        const float ev = encb[(size_t)s2 * TSD];
        c0 = fmaf(p_lds[0][s2], ev, c0);
        c1 = fmaf(p_lds[1][s2], ev, c1);
        c2 = fmaf(p_lds[2][s2], ev, c2);
        c3 = fmaf(p_lds[3][s2], ev, c3);
    }
    const size_t obase = ((size_t)(b * TGT + t0)) * TSD + dh * 256 + tid;
    ctx_out[obase]           = c0;
    ctx_out[obase + TSD]     = c1;
    ctx_out[obase + 2 * TSD] = c2;
    ctx_out[obase + 3 * TSD] = c3;
}

extern "C" void kernel_launch(void* const* d_in, const int* in_sizes, int n_in,
                              void* d_out, int out_size, void* d_ws, size_t ws_size,
                              hipStream_t stream) {
    const float* hid  = (const float*)d_in[0];   // (4,256,512)
    const float* enc  = (const float*)d_in[1];   // (4,256,512)
    const int*   mask = (const int*)  d_in[2];   // (4,256)
    const float* W    = (const float*)d_in[3];   // (512,1024)
    const float* bias = (const float*)d_in[4];   // (512,)
    const float* v    = (const float*)d_in[5];   // (512,)

    float* out   = (float*)d_out;
    float* ctx   = out;                       // 4*256*512
    float* probs = out + NB * TGT * TSD;      // 4*256*256 (holds P, then probs)

    float* hpE2 = (float*)d_ws;               // 1024*512: S*exp2(K*h)/v    2 MB
    float* epE  = hpE2 + NB * TGT * TSD;      // 4*512*256: exp2(K*(e+b))^T 2 MB

    dim3 pb(16, 16);
    dim3 pg(TSD / 64, (NB * TGT) / 64, 2);
    proj_kernel<<<pg, pb, 0, stream>>>(hid, enc, W, bias, v, hpE2, epE);

    dim3 ag(TGT / 4, NB, 2);
    score_kernel<<<ag, 512, 0, stream>>>(hpE2, epE, v, probs);

    softmax_kernel<<<dim3(NB * TGT / 4), 256, 0, stream>>>(mask, v, probs);

    dim3 cg(TGT / 4, NB, 2);
    ctx_kernel<<<cg, 256, 0, stream>>>(probs, enc, ctx);
}